// Round 3
// baseline (185.058 us; speedup 1.0000x reference)
//
#include <hip/hip_runtime.h>

#define Mdim 8
#define Tdim 4000
#define Bdim 128
#define Hdim 512
#define NPER (Tdim*Hdim)
#define EPSG 1e-8f

typedef __attribute__((ext_vector_type(8))) short short8;
typedef __attribute__((ext_vector_type(4))) float floatx4;

static __device__ __forceinline__ float bits2f(unsigned short s) {
  union { unsigned int u; float f; } v; v.u = ((unsigned int)s) << 16; return v.f;
}
static __device__ __forceinline__ unsigned short f2bits(float f) {
  union { float f; unsigned int u; } v; v.f = f;
  unsigned int u = v.u;
  u += 0x7fffu + ((u >> 16) & 1u);   // RNE
  return (unsigned short)(u >> 16);
}
static __device__ __forceinline__ short8 pack8(const float4& a, const float4& b) {
  short8 v;
  v[0]=(short)f2bits(a.x); v[1]=(short)f2bits(a.y); v[2]=(short)f2bits(a.z); v[3]=(short)f2bits(a.w);
  v[4]=(short)f2bits(b.x); v[5]=(short)f2bits(b.y); v[6]=(short)f2bits(b.z); v[7]=(short)f2bits(b.w);
  return v;
}

// wave-local LDS fence: all lanes' ds ops drained; lockstep => covers cross-lane within wave
#define LDS_FENCE() do { \
  asm volatile("s_waitcnt lgkmcnt(0)" ::: "memory"); \
  __builtin_amdgcn_sched_barrier(0); \
} while (0)

// ---------------- K0: one-time weight reformat.
// blocks 0..31: w1 [512,128] f32 -> fragment-ordered bf16 w1r.
// block 32: opw [3,512] f32 -> B-fragment bf16 opwr (16 k-steps, cols>=3 zero).
__global__ __launch_bounds__(256) void k_prep(
    const float* __restrict__ w1, const float* __restrict__ opw,
    unsigned short* __restrict__ w1r, unsigned short* __restrict__ opwr)
{
  const int tid = threadIdx.x;
  if (blockIdx.x < 32) {
    int i = blockIdx.x*256 + tid;            // 8192 short8 fragments
    int lane = i & 63, f = i >> 6;
    int nt = f & 3, ks = (f >> 2) & 3, hc = f >> 4;
    int h = hc*64 + nt*16 + (lane & 15);
    int c = ks*32 + (lane >> 4)*8;
    const float* src = &w1[(size_t)h*Bdim + c];
    float4 a = *(const float4*)src;
    float4 b = *(const float4*)(src + 4);
    *(short8*)&w1r[(size_t)i*8] = pack8(a, b);
  } else {
    #pragma unroll
    for (int it = 0; it < 4; ++it) {
      int idx = it*256 + tid;                // 1024 fragments = 16 ksteps * 64 lanes
      int ks = idx >> 6, lane = idx & 63;
      int l16 = lane & 15, q = lane >> 4;
      int h = ks*32 + q*8;
      float4 a = make_float4(0.f,0.f,0.f,0.f), b = a;
      if (l16 < 3) {
        a = *(const float4*)&opw[(size_t)l16*Hdim + h];
        b = *(const float4*)&opw[(size_t)l16*Hdim + h + 4];
      }
      *(short8*)&opwr[(size_t)idx*8] = pack8(a, b);
    }
  }
}

// ---------------- K1: conv1 GEMM + PReLU + gLN1 partials -> Hbuf [M,T,H] bf16
// 32-t tiles (grid 1000); waves split h-halves; x read once; no block barriers in hot loop.
__global__ __launch_bounds__(256) void k_conv1(
    const float* __restrict__ x,
    const unsigned short* __restrict__ w1r,
    const float* __restrict__ a1p,
    unsigned short* __restrict__ Hbuf,
    float2* __restrict__ part1)
{
  __shared__ __align__(16) unsigned short ltile[4][16*72];
  __shared__ float red[512];

  const int tid = threadIdx.x;
  const int t0 = blockIdx.x * 32;
  const int m  = blockIdx.y;
  const int lane = tid & 63, w = tid >> 6, quad = lane >> 4, l16 = lane & 15;
  const int tsub = w & 1, hh = w >> 1;
  const int tbase = t0 + tsub*16;            // 125*32 = 4000 exactly: no clamps needed
  const float* xrow = x + ((size_t)m*Tdim + tbase + l16)*Bdim;
  short8 afr[4];
  #pragma unroll
  for (int ks = 0; ks < 4; ++ks) {
    float4 fa = *(const float4*)&xrow[ks*32 + quad*8];
    float4 fb = *(const float4*)&xrow[ks*32 + quad*8 + 4];
    afr[ks] = pack8(fa, fb);
  }

  const float a1 = a1p[0];
  const short8* wf = (const short8*)w1r + lane;
  float lsum = 0.f, lss = 0.f;

  #pragma unroll
  for (int hc4 = 0; hc4 < 4; ++hc4) {
    const int hcg = hh*4 + hc4;
    floatx4 acc[4] = {};
    #pragma unroll
    for (int ks = 0; ks < 4; ++ks)
      #pragma unroll
      for (int nt = 0; nt < 4; ++nt)
        acc[nt] = __builtin_amdgcn_mfma_f32_16x16x32_bf16(
            afr[ks], wf[(hcg*16 + ks*4 + nt)*64], acc[nt], 0, 0, 0);

    #pragma unroll
    for (int nt = 0; nt < 4; ++nt) {
      int hl = nt*16 + l16;                  // C/D: col = lane&15
      #pragma unroll
      for (int r = 0; r < 4; ++r) {
        int tl = quad*4 + r;                 // C/D: row = quad*4+reg
        float v = acc[nt][r];
        v = v >= 0.f ? v : a1 * v;
        lsum += v; lss += v*v;
        ltile[w][tl*72 + hl] = f2bits(v);
      }
    }
    LDS_FENCE();   // wave-private transpose tile: writes -> cross-lane reads
    {
      int row = lane >> 2, ck = (lane & 3) * 16;
      unsigned short* dst = &Hbuf[((size_t)m*Tdim + tbase + row)*Hdim + hcg*64 + ck];
      *(short8*)&dst[0] = *(const short8*)&ltile[w][row*72 + ck];
      *(short8*)&dst[8] = *(const short8*)&ltile[w][row*72 + ck + 8];
    }
    LDS_FENCE();   // reads drained before next hc overwrites
  }

  red[tid] = lsum; red[256 + tid] = lss;
  __syncthreads();
  for (int s = 128; s > 0; s >>= 1) {
    if (tid < s) { red[tid] += red[tid + s]; red[256+tid] += red[256+tid+s]; }
    __syncthreads();
  }
  if (tid == 0)
    part1[(size_t)m*125 + blockIdx.x] = make_float2(red[0], red[256]);
}

// ---------------- K1b: reduce part1 -> gLN1 stats; fold into per-(m,h) constants.
// axcx[m][h] = {A, C};  wodc[m][h] = {A*wod0, A*wod1, A*wod2, C*(wod0+wod1+wod2)}
__global__ __launch_bounds__(128) void k_stats1(
    const float2* __restrict__ part1,
    const float* __restrict__ g1w,
    const float* __restrict__ b1w,
    const float* __restrict__ odw,
    float2* __restrict__ axcx,
    float4* __restrict__ wodc)
{
  const int m = blockIdx.x, tid = threadIdx.x, lane = tid & 63, w = tid >> 6;
  __shared__ float sh[4];
  float s = 0.f, q = 0.f;
  if (tid < 125) { float2 p = part1[(size_t)m*125 + tid]; s = p.x; q = p.y; }
  #pragma unroll
  for (int st = 32; st > 0; st >>= 1) { s += __shfl_xor(s, st); q += __shfl_xor(q, st); }
  if (lane == 0) { sh[w*2] = s; sh[w*2+1] = q; }
  __syncthreads();
  const float S = sh[0] + sh[2], Q = sh[1] + sh[3];
  const float invn = 1.0f/(float)NPER;
  const float mean1 = S*invn;
  const float var1  = fmaxf(Q*invn - mean1*mean1, 0.f);
  const float inv1  = 1.0f/sqrtf(var1 + EPSG);
  #pragma unroll
  for (int i = 0; i < 4; ++i) {
    int h = tid*4 + i;
    float A = g1w[h]*inv1;
    float C = b1w[h] - mean1*A;
    axcx[(size_t)m*Hdim + h] = make_float2(A, C);
    float w0 = odw[h*3], w1_ = odw[h*3+1], w2 = odw[h*3+2];
    wodc[(size_t)m*Hdim + h] = make_float4(A*w0, A*w1_, A*w2, C*(w0+w1_+w2));
  }
}

// ---------------- K2a: offset branch via MFMA -> tap params [M,T,3] float4 {g0,g1,ia,ib}
// wave = 16 t; lane computes dwconv'd/PReLU'd d for (t=tbase+l16, h=ks*32+quad*8..+8),
// MFMA reduces over h=512 (16 k-steps) against opw fragments; lanes l16<3 emit taps.
__global__ __launch_bounds__(256) void k_offs(
    const unsigned short* __restrict__ Hbuf,
    const float4* __restrict__ wodc,
    const unsigned short* __restrict__ opwr,
    const float* __restrict__ aodcp,
    const float* __restrict__ aopcp,
    float4* __restrict__ taps)
{
  const int tid = threadIdx.x, lane = tid & 63, w = tid >> 6;
  const int quad = lane >> 4, l16 = lane & 15;
  const int m = blockIdx.y;
  const int tbase = blockIdx.x*64 + w*16;
  int t = tbase + l16;
  int tc = t < Tdim ? t : Tdim-1;
  int tm1 = tc == 0 ? 1 : tc-1;
  int tp1 = tc == Tdim-1 ? Tdim-2 : tc+1;
  const unsigned short* r0p = Hbuf + ((size_t)m*Tdim + tm1)*Hdim;
  const unsigned short* r1p = Hbuf + ((size_t)m*Tdim + tc )*Hdim;
  const unsigned short* r2p = Hbuf + ((size_t)m*Tdim + tp1)*Hdim;
  const float4* wcb = wodc + (size_t)m*Hdim;
  const float aodc = aodcp[0], aopc = aopcp[0];

  floatx4 acc = {};
  #pragma unroll
  for (int g = 0; g < 4; ++g) {
    short8 h0v[4], h1v[4], h2v[4], bop[4];
    #pragma unroll
    for (int k2 = 0; k2 < 4; ++k2) {
      int hc = (g*4 + k2)*32 + quad*8;
      h0v[k2] = *(const short8*)&r0p[hc];
      h1v[k2] = *(const short8*)&r1p[hc];
      h2v[k2] = *(const short8*)&r2p[hc];
      bop[k2] = *(const short8*)&opwr[(size_t)((g*4 + k2)*64 + lane)*8];
    }
    #pragma unroll
    for (int k2 = 0; k2 < 4; ++k2) {
      int hc = (g*4 + k2)*32 + quad*8;
      float d[8];
      #pragma unroll
      for (int j = 0; j < 8; ++j) {
        float4 wc = wcb[hc + j];
        float dv = fmaf(wc.x, bits2f((unsigned short)h0v[k2][j]),
                   fmaf(wc.y, bits2f((unsigned short)h1v[k2][j]),
                   fmaf(wc.z, bits2f((unsigned short)h2v[k2][j]), wc.w)));
        d[j] = dv >= 0.f ? dv : aodc*dv;
      }
      short8 afr = pack8(make_float4(d[0],d[1],d[2],d[3]),
                         make_float4(d[4],d[5],d[6],d[7]));
      acc = __builtin_amdgcn_mfma_f32_16x16x32_bf16(afr, bop[k2], acc, 0, 0, 0);
    }
  }

  if (l16 < 3) {
    #pragma unroll
    for (int r = 0; r < 4; ++r) {
      int tout = tbase + quad*4 + r;         // C/D: row = quad*4+reg, col = l16 (=k)
      if (tout < Tdim) {
        float off = acc[r];
        off = off >= 0.f ? off : aopc*off;
        float tf = (float)tout;
        float pos = tf + (float)(2*l16) + off;
        pos = fminf(fmaxf(pos, tf), tf + 4.0f);
        int U = (int)floorf(pos);
        if (U > Tdim + 2) U = Tdim + 2;      // Lp-2
        float Uf = (float)U;
        float g0 = fmaxf(0.f, 1.f - fabsf(Uf - pos));
        float g1 = fmaxf(0.f, 1.f - fabsf(Uf + 1.f - pos));
        int ia = U - 2; ia = ia < 0 ? -ia : ia; if (ia > Tdim-1) ia = 2*(Tdim-1) - ia;
        int ib = U - 1; ib = ib < 0 ? -ib : ib; if (ib > Tdim-1) ib = 2*(Tdim-1) - ib;
        taps[((size_t)m*Tdim + tout)*3 + l16] =
            make_float4(g0, g1, __int_as_float(ia), __int_as_float(ib));
      }
    }
  }
}

// ---------------- K2b: deformable sampling + PReLU2 + gLN2 partials -> Ybuf
// No serial prefix: taps -> gathers issue immediately. No LDS tile, no barriers.
__global__ __launch_bounds__(256) void k_samp(
    const unsigned short* __restrict__ Hbuf,
    const float4* __restrict__ taps,
    const float2* __restrict__ axcx,
    const float* __restrict__ dww,
    const float* __restrict__ dwb,
    const float* __restrict__ a2p,
    unsigned short* __restrict__ Ybuf,
    float2* __restrict__ part2)
{
  __shared__ float rsum[4], rss[4];
  const int tid = threadIdx.x, lane = tid & 63, w = tid >> 6;
  const int tb = blockIdx.x*8 + w*2;
  const int m = blockIdx.y;
  const int c8 = lane*8;
  const unsigned short* base = Hbuf + (size_t)m*Tdim*Hdim;

  const float4* tp = taps + ((size_t)m*Tdim + tb)*3;
  float4 tq[6];
  #pragma unroll
  for (int i = 0; i < 6; ++i) tq[i] = tp[i];

  float G0[2][3], G1[2][3], GS[2][3];
  short8 s0v[2][3], s1v[2][3];
  #pragma unroll
  for (int tt = 0; tt < 2; ++tt)
    #pragma unroll
    for (int k = 0; k < 3; ++k) {
      float4 q = tq[tt*3 + k];
      G0[tt][k] = q.x; G1[tt][k] = q.y; GS[tt][k] = q.x + q.y;
      int ia = __float_as_int(q.z), ib = __float_as_int(q.w);
      s0v[tt][k] = *(const short8*)&base[(size_t)ia*Hdim + c8];
      s1v[tt][k] = *(const short8*)&base[(size_t)ib*Hdim + c8];
    }

  float wd[24], bv[8], Ax[8], Cx[8];
  #pragma unroll
  for (int j = 0; j < 24; j += 4)
    *(float4*)&wd[j] = *(const float4*)&dww[c8*3 + j];
  #pragma unroll
  for (int j = 0; j < 8; j += 4)
    *(float4*)&bv[j] = *(const float4*)&dwb[c8 + j];
  #pragma unroll
  for (int j = 0; j < 8; j += 2) {
    float4 ac = *(const float4*)&axcx[(size_t)m*Hdim + c8 + j];
    Ax[j] = ac.x; Cx[j] = ac.y; Ax[j+1] = ac.z; Cx[j+1] = ac.w;
  }
  const float a2 = a2p[0];

  float lsum = 0.f, lss = 0.f;
  short8 yv[2];
  #pragma unroll
  for (int j = 0; j < 8; ++j) {
    float A = Ax[j], C = Cx[j];
    float w0 = wd[j*3+0], w1 = wd[j*3+1], w2 = wd[j*3+2];
    #pragma unroll
    for (int tt = 0; tt < 2; ++tt) {
      float ybase = fmaf(C, w0*GS[tt][0] + w1*GS[tt][1] + w2*GS[tt][2], bv[j]);
      float t0s = fmaf(G1[tt][0], bits2f((unsigned short)s1v[tt][0][j]), G0[tt][0]*bits2f((unsigned short)s0v[tt][0][j]));
      float t1s = fmaf(G1[tt][1], bits2f((unsigned short)s1v[tt][1][j]), G0[tt][1]*bits2f((unsigned short)s0v[tt][1][j]));
      float t2s = fmaf(G1[tt][2], bits2f((unsigned short)s1v[tt][2][j]), G0[tt][2]*bits2f((unsigned short)s0v[tt][2][j]));
      float acc2 = w0*t0s + w1*t1s + w2*t2s;
      float y = fmaf(A, acc2, ybase);
      float p = y >= 0.f ? y : a2*y;
      lsum += p; lss += p*p;
      yv[tt][j] = (short)f2bits(p);
    }
  }
  #pragma unroll
  for (int tt = 0; tt < 2; ++tt)
    *(short8*)&Ybuf[((size_t)m*Tdim + tb + tt)*Hdim + c8] = yv[tt];

  #pragma unroll
  for (int st = 32; st > 0; st >>= 1) {
    lsum += __shfl_xor(lsum, st);
    lss  += __shfl_xor(lss, st);
  }
  if (lane == 0) { rsum[w] = lsum; rss[w] = lss; }
  __syncthreads();
  if (tid == 0)
    part2[(size_t)m*500 + blockIdx.x] =
      make_float2(rsum[0]+rsum[1]+rsum[2]+rsum[3], rss[0]+rss[1]+rss[2]+rss[3]);
}

// ---------------- K3: reduce part2 + fold gLN2 into pointwise weights; emit W2 in FRAGMENT order
__global__ __launch_bounds__(64) void k_w2(
    const float2* __restrict__ part2,
    const float* __restrict__ g2w,
    const float* __restrict__ b2w,
    const float* __restrict__ pww,
    unsigned short* __restrict__ W2r,
    float* __restrict__ const2)
{
  const int bid = blockIdx.x;
  const int m = bid >> 7, b = bid & 127;
  const int tid = threadIdx.x;

  float s = 0.f, q = 0.f;
  for (int i = tid; i < 500; i += 64) {
    float2 p = part2[(size_t)m*500 + i];
    s += p.x; q += p.y;
  }
  #pragma unroll
  for (int st = 32; st > 0; st >>= 1) { s += __shfl_xor(s, st); q += __shfl_xor(q, st); }

  const float invn = 1.0f/(float)NPER;
  const float mean2 = s*invn;
  const float var2  = fmaxf(q*invn - mean2*mean2, 0.f);
  const float inv2  = 1.0f/sqrtf(var2 + EPSG);

  const int j8 = tid*8;
  float g2v[8], b2v[8], pv[8];
  #pragma unroll
  for (int j = 0; j < 8; j += 4) {
    *(float4*)&g2v[j] = *(const float4*)&g2w[j8 + j];
    *(float4*)&b2v[j] = *(const float4*)&b2w[j8 + j];
    *(float4*)&pv[j]  = *(const float4*)&pww[(size_t)b*Hdim + j8 + j];
  }
  float csum = 0.f;
  short8 wv8;
  #pragma unroll
  for (int j = 0; j < 8; ++j) {
    float A = g2v[j] * inv2;
    float C = b2v[j] - mean2*A;
    csum = fmaf(C, pv[j], csum);
    wv8[j] = (short)f2bits(A*pv[j]);
  }
  {
    int half = b >> 6, nt = (b >> 4) & 3, l16 = b & 15;
    int kc = tid >> 4, ks = (tid >> 2) & 3, quad = tid & 3;
    int lane = quad*16 + l16;
    size_t f = ((((size_t)(m*2 + half)*4 + kc)*4 + ks)*4 + nt);
    *(short8*)&W2r[(f*64 + lane)*8] = wv8;
  }

  #pragma unroll
  for (int st = 32; st > 0; st >>= 1) csum += __shfl_down(csum, st);
  if (tid == 0) const2[m*Bdim + b] = csum;
}

// ---------------- K4: final GEMM Ybuf @ W2^T + const2 + residual -> out f32
__global__ __launch_bounds__(256) void k_out(
    const unsigned short* __restrict__ Ybuf,
    const unsigned short* __restrict__ W2r,
    const float* __restrict__ const2,
    const float* __restrict__ x,
    float* __restrict__ out)
{
  __shared__ __align__(16) float ltf[64*68];
  const int tid = threadIdx.x;
  const int t0 = blockIdx.x*64;
  const int half = blockIdx.y;
  const int n0 = half*64;
  const int m  = blockIdx.z;
  const int lane = tid & 63, wv = tid >> 6, quad = lane >> 4, l16 = lane & 15;
  int tr = t0 + wv*16 + l16;
  int trc = tr < Tdim ? tr : Tdim-1;
  const unsigned short* arow = Ybuf + ((size_t)m*Tdim + trc)*Hdim;
  const short8* wf = (const short8*)W2r + (size_t)(m*2 + half)*64*64 + lane;

  floatx4 acc[4] = {};
  #pragma unroll
  for (int kc = 0; kc < 4; ++kc)
    #pragma unroll
    for (int ks = 0; ks < 4; ++ks) {
      short8 afr = *(const short8*)&arow[kc*128 + ks*32 + quad*8];
      #pragma unroll
      for (int nt = 0; nt < 4; ++nt)
        acc[nt] = __builtin_amdgcn_mfma_f32_16x16x32_bf16(
            afr, wf[((kc*4 + ks)*4 + nt)*64], acc[nt], 0, 0, 0);
    }

  #pragma unroll
  for (int nt = 0; nt < 4; ++nt) {
    int bl = nt*16 + l16;
    float cb = const2[m*Bdim + n0 + bl];
    #pragma unroll
    for (int r = 0; r < 4; ++r) {
      int tl = wv*16 + quad*4 + r;
      ltf[tl*68 + bl] = acc[nt][r] + cb;
    }
  }
  LDS_FENCE();   // wave-private transpose: write -> read
  {
    int tr2 = tid >> 2, ck = (tid & 3) * 16;
    int tg = t0 + tr2;
    if (tg < Tdim) {
      const float* xr = &x[((size_t)m*Tdim + tg)*Bdim + n0 + ck];
      float* orow = &out[((size_t)m*Tdim + tg)*Bdim + n0 + ck];
      #pragma unroll
      for (int j = 0; j < 4; ++j) {
        float4 v = *(const float4*)&ltf[tr2*68 + ck + j*4];
        float4 rx = *(const float4*)&xr[j*4];
        v.x += rx.x; v.y += rx.y; v.z += rx.z; v.w += rx.w;
        *(float4*)&orow[j*4] = v;
      }
    }
  }
}

extern "C" void kernel_launch(void* const* d_in, const int* in_sizes, int n_in,
                              void* d_out, int out_size, void* d_ws, size_t ws_size,
                              hipStream_t stream)
{
  (void)in_sizes; (void)n_in; (void)out_size; (void)ws_size;
  const float* x    = (const float*)d_in[0];
  const float* w1   = (const float*)d_in[1];
  const float* a1   = (const float*)d_in[2];
  const float* g1   = (const float*)d_in[3];
  const float* b1   = (const float*)d_in[4];
  const float* odw  = (const float*)d_in[5];
  const float* aodc = (const float*)d_in[6];
  const float* opw  = (const float*)d_in[7];
  const float* aopc = (const float*)d_in[8];
  const float* dww  = (const float*)d_in[9];
  const float* dwb  = (const float*)d_in[10];
  const float* a2   = (const float*)d_in[11];
  const float* g2   = (const float*)d_in[12];
  const float* b2   = (const float*)d_in[13];
  const float* pww  = (const float*)d_in[14];
  float* out = (float*)d_out;

  char* ws = (char*)d_ws;
  const size_t OFF_P1   = 0;          // part1 [8,125] float2: 8000 B
  const size_t OFF_P2   = 8192;       // part2 [8,500] float2: 32000 B
  const size_t OFF_C2   = 40960;      // const2 [8,128] f32: 4096 B
  const size_t OFF_AXCX = 45056;      // axcx [8,512] float2: 32768 B
  const size_t OFF_WODC = 77824;      // wodc [8,512] float4: 65536 B
  const size_t OFF_W1R  = 143360;     // w1r fragment bf16: 131072 B
  const size_t OFF_OPWR = 274432;     // opwr fragment bf16: 16384 B
  const size_t OFF_TAPS = 290816;     // taps [8,4000,3] float4: 1536000 B
  const size_t OFF_W2   = 1826816;    // W2r [8,128,512] bf16 fragment order: 1048576 B
  const size_t OFF_H    = 2875392;    // Hbuf [8,4000,512] bf16: 32768000 B
  const size_t OFF_Y    = 35643392;   // Ybuf [8,4000,512] bf16: 32768000 B
  float2* part1  = (float2*)(ws + OFF_P1);
  float2* part2  = (float2*)(ws + OFF_P2);
  float*  const2 = (float*)(ws + OFF_C2);
  float2* axcx   = (float2*)(ws + OFF_AXCX);
  float4* wodc   = (float4*)(ws + OFF_WODC);
  unsigned short* w1r  = (unsigned short*)(ws + OFF_W1R);
  unsigned short* opwr = (unsigned short*)(ws + OFF_OPWR);
  float4* taps   = (float4*)(ws + OFF_TAPS);
  unsigned short* W2r  = (unsigned short*)(ws + OFF_W2);
  unsigned short* Hbuf = (unsigned short*)(ws + OFF_H);
  unsigned short* Ybuf = (unsigned short*)(ws + OFF_Y);

  k_prep  <<<dim3(33), 256, 0, stream>>>(w1, opw, w1r, opwr);
  k_conv1 <<<dim3(125, 8), 256, 0, stream>>>(x, w1r, a1, Hbuf, part1);
  k_stats1<<<dim3(8), 128, 0, stream>>>(part1, g1, b1, odw, axcx, wodc);
  k_offs  <<<dim3(63, 8), 256, 0, stream>>>(Hbuf, wodc, opwr, aodc, aopc, taps);
  k_samp  <<<dim3(500, 8), 256, 0, stream>>>(Hbuf, taps, axcx, dww, dwb, a2, Ybuf, part2);
  k_w2    <<<dim3(1024), 64, 0, stream>>>(part2, g2, b2, pww, W2r, const2);
  k_out   <<<dim3(63, 2, 8), 256, 0, stream>>>(Ybuf, W2r, const2, x, out);
}